// Round 4
// baseline (855.542 us; speedup 1.0000x reference)
//
#include <hip/hip_runtime.h>

typedef _Float16 f16;
typedef _Float16 half8 __attribute__((ext_vector_type(8)));
typedef _Float16 half4 __attribute__((ext_vector_type(4)));
typedef float f32x4 __attribute__((ext_vector_type(4)));

#define B_ 2
#define S_ 2048
#define DM_ 2048
#define H_ 16
#define HD_ 128
#define EQ_ 6144              // (H + 2*HKV) * HD = 48*128
#define SCALE_Q 0.08838834764831845f   // 1/sqrt(128); natural-log softmax, __expf is fast
#define DEFER_THR 8.0f

// async global->LDS, 16B per lane; LDS dest is wave-uniform base + lane*16
__device__ __forceinline__ void gload16(const void* g, void* l) {
  __builtin_amdgcn_global_load_lds(
      (const __attribute__((address_space(1))) unsigned int*)g,
      (__attribute__((address_space(3))) unsigned int*)l, 16, 0, 0);
}

// 16-lane reductions via DPP (VALU-speed, no DS pipe): xor1, xor2, then
// half_mirror (==xor4 effect once quads uniform), mirror (==xor8 effect).
__device__ __forceinline__ float red16_max(float x) {
  float t;
  t = __builtin_bit_cast(float, __builtin_amdgcn_mov_dpp(__builtin_bit_cast(int, x), 0xB1, 0xF, 0xF, true));
  x = fmaxf(x, t);
  t = __builtin_bit_cast(float, __builtin_amdgcn_mov_dpp(__builtin_bit_cast(int, x), 0x4E, 0xF, 0xF, true));
  x = fmaxf(x, t);
  t = __builtin_bit_cast(float, __builtin_amdgcn_mov_dpp(__builtin_bit_cast(int, x), 0x141, 0xF, 0xF, true));
  x = fmaxf(x, t);
  t = __builtin_bit_cast(float, __builtin_amdgcn_mov_dpp(__builtin_bit_cast(int, x), 0x140, 0xF, 0xF, true));
  x = fmaxf(x, t);
  return x;
}
__device__ __forceinline__ float red16_sum(float x) {
  float t;
  t = __builtin_bit_cast(float, __builtin_amdgcn_mov_dpp(__builtin_bit_cast(int, x), 0xB1, 0xF, 0xF, true));
  x += t;
  t = __builtin_bit_cast(float, __builtin_amdgcn_mov_dpp(__builtin_bit_cast(int, x), 0x4E, 0xF, 0xF, true));
  x += t;
  t = __builtin_bit_cast(float, __builtin_amdgcn_mov_dpp(__builtin_bit_cast(int, x), 0x141, 0xF, 0xF, true));
  x += t;
  t = __builtin_bit_cast(float, __builtin_amdgcn_mov_dpp(__builtin_bit_cast(int, x), 0x140, 0xF, 0xF, true));
  x += t;
  return x;
}

// ---------------- cast fp32 -> fp16 (same layout) ----------------
__global__ void k_cast(const float* __restrict__ in, f16* __restrict__ out, int n4) {
  int i = blockIdx.x * blockDim.x + threadIdx.x;
  int stride = gridDim.x * blockDim.x;
  for (; i < n4; i += stride) {
    float4 v = ((const float4*)in)[i];
    half4 h = { (f16)v.x, (f16)v.y, (f16)v.z, (f16)v.w };
    ((half4*)out)[i] = h;
  }
}

// ------------- transpose+cast: in[K][N] fp32 -> out[N][K] fp16 -------------
__global__ void k_tcast(const float* __restrict__ in, f16* __restrict__ out, int K, int N) {
  __shared__ float tile[64][65];
  const int t = threadIdx.x;
  const int nb = blockIdx.x * 64, kb = blockIdx.y * 64;
  const int tr = t >> 4, tc4 = (t & 15) * 4;
  #pragma unroll
  for (int i = 0; i < 4; ++i) {
    int k = tr + i * 16;
    float4 v = *(const float4*)&in[(size_t)(kb + k) * N + nb + tc4];
    tile[k][tc4 + 0] = v.x; tile[k][tc4 + 1] = v.y;
    tile[k][tc4 + 2] = v.z; tile[k][tc4 + 3] = v.w;
  }
  __syncthreads();
  #pragma unroll
  for (int i = 0; i < 4; ++i) {
    int n = tr + i * 16;
    half4 h = { (f16)tile[tc4 + 0][n], (f16)tile[tc4 + 1][n],
                (f16)tile[tc4 + 2][n], (f16)tile[tc4 + 3][n] };
    *(half4*)&out[(size_t)(nb + n) * K + kb + tc4] = h;
  }
}

// ---------------- fp16 MFMA GEMM: C[M][N] = A[M][K] * Bt[N][K]^T ----------------
// m97 structure: 128x128 tile, BK=64, 4 waves (2x2 of 64x64),
// global_load_lds staging into LINEAR LDS, 2 barriers per K-step.
__global__ __launch_bounds__(256, 2) void k_gemm(
    const f16* __restrict__ A, const f16* __restrict__ Bt,
    f16* __restrict__ C16, float* __restrict__ C32,
    int M, int N, int K, int writeF32)
{
  __shared__ __attribute__((aligned(16))) f16 As[128 * 64];
  __shared__ __attribute__((aligned(16))) f16 Bs[128 * 64];
  const int t = threadIdx.x;
  const int lane = t & 63, wave = t >> 6;
  const int lr = lane & 15, hi4 = lane >> 4;
  const int wr = wave >> 1, wc = wave & 1;
  const int row0 = blockIdx.x * 128, col0 = blockIdx.y * 128;

  const int srow = lane >> 3, schunk = lane & 7;
  const f16* gA = &A[(size_t)(row0 + wave * 32 + srow) * K + schunk * 8];
  const f16* gB = &Bt[(size_t)(col0 + wave * 32 + srow) * K + schunk * 8];
  char* asb = (char*)As;
  char* bsb = (char*)Bs;

  f32x4 acc[4][4];
  #pragma unroll
  for (int m = 0; m < 4; ++m)
    #pragma unroll
    for (int n = 0; n < 4; ++n)
      acc[m][n] = (f32x4){0.f, 0.f, 0.f, 0.f};

  const int nk = K >> 6;
  for (int kt = 0; kt < nk; ++kt) {
    __syncthreads();
    #pragma unroll
    for (int i = 0; i < 4; ++i) {
      gload16(gA + (size_t)(i * 8) * K + kt * 64, asb + wave * 4096 + i * 1024);
      gload16(gB + (size_t)(i * 8) * K + kt * 64, bsb + wave * 4096 + i * 1024);
    }
    __syncthreads();
    #pragma unroll
    for (int ks = 0; ks < 2; ++ks) {
      half8 af[4], bf[4];
      #pragma unroll
      for (int m = 0; m < 4; ++m)
        af[m] = *(const half8*)(asb + (wr * 64 + m * 16 + lr) * 128 + ks * 64 + hi4 * 16);
      #pragma unroll
      for (int n = 0; n < 4; ++n)
        bf[n] = *(const half8*)(bsb + (wc * 64 + n * 16 + lr) * 128 + ks * 64 + hi4 * 16);
      #pragma unroll
      for (int m = 0; m < 4; ++m)
        #pragma unroll
        for (int n = 0; n < 4; ++n)
          acc[m][n] = __builtin_amdgcn_mfma_f32_16x16x32_f16(af[m], bf[n], acc[m][n], 0, 0, 0);
    }
  }
  #pragma unroll
  for (int m = 0; m < 4; ++m)
    #pragma unroll
    for (int n = 0; n < 4; ++n)
      #pragma unroll
      for (int j = 0; j < 4; ++j) {
        int row = row0 + wr * 64 + m * 16 + hi4 * 4 + j;
        int col = col0 + wc * 64 + n * 16 + lr;
        if (writeF32) C32[(size_t)row * N + col] = acc[m][n][j];
        else          C16[(size_t)row * N + col] = (f16)acc[m][n][j];
      }
  (void)M;
}

// ---------------- RoPE on q,k heads; writes Q (scaled) and K ----------------
__global__ void k_rope(const f16* __restrict__ qkv, const float* __restrict__ cosb,
                       const float* __restrict__ sinb, f16* __restrict__ Qf, f16* __restrict__ Kf)
{
  const int bx = blockIdx.x;              // B*S*16
  const int bs = bx >> 4;
  const int h = (bx & 15) * 2 + (threadIdx.x >> 7);   // 0..31 (q:0-15, k:16-31)
  const int d = threadIdx.x & 127;
  const int s = bs & (S_ - 1);
  const int b = bs >> 11;
  float x  = (float)qkv[(size_t)bs * EQ_ + h * HD_ + d];
  float xp = (float)qkv[(size_t)bs * EQ_ + h * HD_ + (d ^ 64)];
  float sgn = (d < 64) ? -1.0f : 1.0f;
  float v = x * cosb[s * HD_ + d] + sgn * xp * sinb[s * HD_ + d];
  if (h < H_) {
    v *= SCALE_Q;
    Qf[(((size_t)(b * H_ + h)) * S_ + s) * HD_ + d] = (f16)v;
  } else {
    Kf[(((size_t)(b * H_ + (h - H_))) * S_ + s) * HD_ + d] = (f16)v;
  }
}

// ---------------- V transpose: qkv v-heads -> VT[B][H][D][S] fp16 ----------------
__global__ void k_vtrans(const f16* __restrict__ qkv, f16* __restrict__ VT)
{
  __shared__ __attribute__((aligned(16))) f16 tile[128][136];
  const int bx = blockIdx.x;              // B*H*(S/128) = 512
  const int st = bx & 15, h = (bx >> 4) & 15, b = bx >> 8;
  const int t = threadIdx.x;
  const int sl = t >> 1, dc = (t & 1) * 64;
  const int bs = b * S_ + st * 128 + sl;
  #pragma unroll
  for (int i = 0; i < 8; ++i) {
    half8 v = *(const half8*)&qkv[(size_t)bs * EQ_ + (32 + h) * HD_ + dc + i * 8];
    *(half8*)&tile[sl][dc + i * 8] = v;
  }
  __syncthreads();
  const int dr = t >> 1, scc = (t & 1) * 64;
  #pragma unroll
  for (int i = 0; i < 8; ++i) {
    half8 v;
    #pragma unroll
    for (int j = 0; j < 8; ++j) v[j] = tile[scc + i * 8 + j][dr];
    *(half8*)&VT[(((size_t)(b * H_ + h)) * HD_ + dr) * S_ + st * 128 + scc + i * 8] = v;
  }
}

// ---------------- flash attention: 4 waves x 32 q-rows, KT=64 ----------------
// 32KB LDS (P reuses Ks region after QK), 4 blocks/CU, gload_lds staging with
// pre-swizzled global source (rule #21), DPP reductions, defer-max (T13).
__global__ __launch_bounds__(256, 4) void k_attn(
    const f16* __restrict__ Qf, const f16* __restrict__ Kf, const f16* __restrict__ VT,
    f16* __restrict__ Oout)
{
  __shared__ __attribute__((aligned(16))) char lds[32768];
  char* Ks = lds;                        // [64 tok][128 d], 256B rows, chunk^(row&7)
  char* Vs = lds + 16384;                // [128 d][64 tok], 128B rows, chunk^(row&7)
  const int bx = blockIdx.x;             // B*H*(S/128) = 512
  const int qt = bx & 15, h = (bx >> 4) & 15, b = bx >> 8;
  const int t = threadIdx.x, lane = t & 63, wave = t >> 6;
  const int lr = lane & 15, hi4 = lane >> 4;
  char* Ps = Ks + wave * 4096;           // after QK: per-wave [32 q][64 tok] swizzled
  const size_t bh = (size_t)(b * H_ + h);
  const int q0 = qt * 128 + wave * 32;

  half8 qf[2][4];
  #pragma unroll
  for (int m = 0; m < 2; ++m)
    #pragma unroll
    for (int ds = 0; ds < 4; ++ds)
      qf[m][ds] = *(const half8*)&Qf[(bh * S_ + q0 + m * 16 + lr) * HD_ + ds * 32 + hi4 * 8];

  f32x4 o[2][8];
  #pragma unroll
  for (int m = 0; m < 2; ++m)
    #pragma unroll
    for (int dc = 0; dc < 8; ++dc) o[m][dc] = (f32x4){0.f, 0.f, 0.f, 0.f};
  float mstate[2][4], lstate[2][4];
  #pragma unroll
  for (int m = 0; m < 2; ++m)
    #pragma unroll
    for (int j = 0; j < 4; ++j) { mstate[m][j] = -1e30f; lstate[m][j] = 0.f; }

  const f16* Kg = &Kf[bh * S_ * HD_];
  const f16* Vg = &VT[bh * HD_ * S_];

  for (int kt = 0; kt < S_ / 64; ++kt) {
    __syncthreads();
    // K stage: wave w covers rows w*16..w*16+15; LDS linear = base + lane*16;
    // global chunk pre-swizzled so LDS[row][c] = K[row][c ^ (row&7)]
    #pragma unroll
    for (int i = 0; i < 4; ++i) {
      int row = wave * 16 + i * 4 + (lane >> 4);
      int ch  = (lane & 15) ^ (row & 7);
      gload16(Kg + (size_t)(kt * 64 + row) * HD_ + ch * 8, Ks + wave * 4096 + i * 1024);
    }
    // V stage: wave w covers d-rows w*32..w*32+31
    #pragma unroll
    for (int i = 0; i < 4; ++i) {
      int d  = wave * 32 + i * 8 + (lane >> 3);
      int ch = (lane & 7) ^ (d & 7);
      gload16(Vg + (size_t)d * S_ + kt * 64 + ch * 8, Vs + wave * 4096 + i * 1024);
    }
    __syncthreads();   // drains vmcnt; staged K/V visible

    f32x4 sc[2][4];
    #pragma unroll
    for (int m = 0; m < 2; ++m)
      #pragma unroll
      for (int n = 0; n < 4; ++n) sc[m][n] = (f32x4){0.f, 0.f, 0.f, 0.f};
    #pragma unroll
    for (int ds = 0; ds < 4; ++ds) {
      half8 kf[4];
      #pragma unroll
      for (int n = 0; n < 4; ++n) {
        int ar = n * 16 + lr;
        kf[n] = *(const half8*)(Ks + ar * 256 + ((((ds * 4 + hi4) ^ (ar & 7))) << 4));
      }
      #pragma unroll
      for (int m = 0; m < 2; ++m)
        #pragma unroll
        for (int n = 0; n < 4; ++n)
          sc[m][n] = __builtin_amdgcn_mfma_f32_16x16x32_f16(qf[m][ds], kf[n], sc[m][n], 0, 0, 0);
    }
    __syncthreads();   // all Ks reads complete; Ks region now reusable for P

    // ---- online softmax (natural log, __expf fast path, DPP reductions) ----
    float mx[2][4];
    #pragma unroll
    for (int m = 0; m < 2; ++m)
      #pragma unroll
      for (int j = 0; j < 4; ++j) {
        mx[m][j] = fmaxf(fmaxf(sc[m][0][j], sc[m][1][j]), fmaxf(sc[m][2][j], sc[m][3][j]));
        mx[m][j] = red16_max(mx[m][j]);
      }
    // defer-max: skip rescale unless some row's max grew by > THR
    float dmax = -1e30f;
    #pragma unroll
    for (int m = 0; m < 2; ++m)
      #pragma unroll
      for (int j = 0; j < 4; ++j)
        dmax = fmaxf(dmax, mx[m][j] - mstate[m][j]);
    if (__any(dmax > DEFER_THR)) {
      #pragma unroll
      for (int m = 0; m < 2; ++m)
        #pragma unroll
        for (int j = 0; j < 4; ++j) {
          float nm = fmaxf(mstate[m][j], mx[m][j]);
          float corr = __expf(mstate[m][j] - nm);
          mstate[m][j] = nm;
          lstate[m][j] *= corr;
          #pragma unroll
          for (int dc = 0; dc < 8; ++dc) o[m][dc][j] *= corr;
        }
    }
    float rs[2][4];
    #pragma unroll
    for (int m = 0; m < 2; ++m)
      #pragma unroll
      for (int j = 0; j < 4; ++j) rs[m][j] = 0.f;
    #pragma unroll
    for (int m = 0; m < 2; ++m)
      #pragma unroll
      for (int n = 0; n < 4; ++n)
        #pragma unroll
        for (int j = 0; j < 4; ++j) {
          float p = __expf(sc[m][n][j] - mstate[m][j]);
          sc[m][n][j] = p;
          rs[m][j] += p;
        }
    #pragma unroll
    for (int m = 0; m < 2; ++m)
      #pragma unroll
      for (int j = 0; j < 4; ++j)
        lstate[m][j] += red16_sum(rs[m][j]);

    // ---- P -> per-wave LDS (fp16, swizzled, in Ks region) ----
    #pragma unroll
    for (int m = 0; m < 2; ++m)
      #pragma unroll
      for (int n = 0; n < 4; ++n)
        #pragma unroll
        for (int j = 0; j < 4; ++j) {
          int prow = m * 16 + hi4 * 4 + j;
          *(f16*)(Ps + prow * 128 + ((n * 32 + lr * 2) ^ ((prow & 7) << 4))) = (f16)sc[m][n][j];
        }
    asm volatile("" ::: "memory");  // per-wave LDS ordering: DS ops in-order per wave

    #pragma unroll
    for (int ks = 0; ks < 2; ++ks) {
      half8 pa[2];
      #pragma unroll
      for (int m = 0; m < 2; ++m) {
        int pr = m * 16 + lr;
        pa[m] = *(const half8*)(Ps + pr * 128 + ((((ks * 4 + hi4) ^ (pr & 7))) << 4));
      }
      #pragma unroll
      for (int dc = 0; dc < 8; ++dc) {
        int rv = dc * 16 + lr;
        half8 vb = *(const half8*)(Vs + rv * 128 + ((((ks * 4 + hi4) ^ (rv & 7))) << 4));
        #pragma unroll
        for (int m = 0; m < 2; ++m)
          o[m][dc] = __builtin_amdgcn_mfma_f32_16x16x32_f16(pa[m], vb, o[m][dc], 0, 0, 0);
      }
    }
  }

  float inv[2][4];
  #pragma unroll
  for (int m = 0; m < 2; ++m)
    #pragma unroll
    for (int j = 0; j < 4; ++j) inv[m][j] = 1.0f / lstate[m][j];
  #pragma unroll
  for (int m = 0; m < 2; ++m)
    #pragma unroll
    for (int dc = 0; dc < 8; ++dc)
      #pragma unroll
      for (int j = 0; j < 4; ++j) {
        int row = b * S_ + qt * 128 + wave * 32 + m * 16 + hi4 * 4 + j;
        int col = h * 128 + dc * 16 + lr;
        Oout[(size_t)row * DM_ + col] = (f16)(o[m][dc][j] * inv[m][j]);
      }
}

extern "C" void kernel_launch(void* const* d_in, const int* in_sizes, int n_in,
                              void* d_out, int out_size, void* d_ws, size_t ws_size,
                              hipStream_t stream) {
  (void)in_sizes; (void)n_in; (void)out_size; (void)ws_size;
  const float* hidden = (const float*)d_in[0];
  const float* cosb   = (const float*)d_in[1];
  const float* sinb   = (const float*)d_in[2];
  const float* W_qkv  = (const float*)d_in[3];
  const float* W_o    = (const float*)d_in[4];
  float* out = (float*)d_out;

  f16* Ah    = (f16*)d_ws;                 // [4096][2048]
  f16* Wqt   = Ah    + (size_t)8388608;    // [6144][2048]
  f16* Wot   = Wqt   + (size_t)12582912;   // [2048][2048]
  f16* qkv16 = Wot   + (size_t)4194304;    // [4096][6144]
  f16* Qf    = qkv16 + (size_t)25165824;   // [2][16][2048][128]
  f16* Kf    = Qf    + (size_t)8388608;
  f16* VT    = Kf    + (size_t)8388608;    // [2][16][128][2048]
  f16* AO    = VT    + (size_t)8388608;    // [4096][2048]

  k_cast<<<2048, 256, 0, stream>>>(hidden, Ah, 2097152);
  k_tcast<<<dim3(EQ_ / 64, 2048 / 64), 256, 0, stream>>>(W_qkv, Wqt, 2048, EQ_);
  k_tcast<<<dim3(2048 / 64, 2048 / 64), 256, 0, stream>>>(W_o, Wot, 2048, 2048);
  k_gemm<<<dim3(32, EQ_ / 128), 256, 0, stream>>>(Ah, Wqt, qkv16, nullptr, 4096, EQ_, 2048, 0);
  k_rope<<<B_ * S_ * 16, 256, 0, stream>>>(qkv16, cosb, sinb, Qf, Kf);
  k_vtrans<<<512, 256, 0, stream>>>(qkv16, VT);
  k_attn<<<512, 256, 0, stream>>>(Qf, Kf, VT, AO);
  k_gemm<<<dim3(32, 16), 256, 0, stream>>>(AO, Wot, nullptr, out, 4096, 2048, 2048, 1);
}

// Round 5
// 459.649 us; speedup vs baseline: 1.8613x; 1.8613x over previous
//
#include <hip/hip_runtime.h>

typedef _Float16 f16;
typedef _Float16 half8 __attribute__((ext_vector_type(8)));
typedef _Float16 half4 __attribute__((ext_vector_type(4)));
typedef float f32x4 __attribute__((ext_vector_type(4)));

#define B_ 2
#define S_ 2048
#define DM_ 2048
#define H_ 16
#define HD_ 128
#define EQ_ 6144              // (H + 2*HKV) * HD = 48*128
#define SCALE_Q 0.08838834764831845f   // 1/sqrt(128); natural-log softmax, __expf is fast
#define DEFER_THR 8.0f

// async global->LDS, 16B per lane; LDS dest is wave-uniform base + lane*16
__device__ __forceinline__ void gload16(const void* g, void* l) {
  __builtin_amdgcn_global_load_lds(
      (const __attribute__((address_space(1))) unsigned int*)g,
      (__attribute__((address_space(3))) unsigned int*)l, 16, 0, 0);
}

// 16-lane reductions via DPP (VALU-speed, no DS pipe)
__device__ __forceinline__ float red16_max(float x) {
  float t;
  t = __builtin_bit_cast(float, __builtin_amdgcn_mov_dpp(__builtin_bit_cast(int, x), 0xB1, 0xF, 0xF, true));
  x = fmaxf(x, t);
  t = __builtin_bit_cast(float, __builtin_amdgcn_mov_dpp(__builtin_bit_cast(int, x), 0x4E, 0xF, 0xF, true));
  x = fmaxf(x, t);
  t = __builtin_bit_cast(float, __builtin_amdgcn_mov_dpp(__builtin_bit_cast(int, x), 0x141, 0xF, 0xF, true));
  x = fmaxf(x, t);
  t = __builtin_bit_cast(float, __builtin_amdgcn_mov_dpp(__builtin_bit_cast(int, x), 0x140, 0xF, 0xF, true));
  x = fmaxf(x, t);
  return x;
}
__device__ __forceinline__ float red16_sum(float x) {
  float t;
  t = __builtin_bit_cast(float, __builtin_amdgcn_mov_dpp(__builtin_bit_cast(int, x), 0xB1, 0xF, 0xF, true));
  x += t;
  t = __builtin_bit_cast(float, __builtin_amdgcn_mov_dpp(__builtin_bit_cast(int, x), 0x4E, 0xF, 0xF, true));
  x += t;
  t = __builtin_bit_cast(float, __builtin_amdgcn_mov_dpp(__builtin_bit_cast(int, x), 0x141, 0xF, 0xF, true));
  x += t;
  t = __builtin_bit_cast(float, __builtin_amdgcn_mov_dpp(__builtin_bit_cast(int, x), 0x140, 0xF, 0xF, true));
  x += t;
  return x;
}

// ---------------- cast fp32 -> fp16 (same layout) ----------------
__global__ void k_cast(const float* __restrict__ in, f16* __restrict__ out, int n4) {
  int i = blockIdx.x * blockDim.x + threadIdx.x;
  int stride = gridDim.x * blockDim.x;
  for (; i < n4; i += stride) {
    float4 v = ((const float4*)in)[i];
    half4 h = { (f16)v.x, (f16)v.y, (f16)v.z, (f16)v.w };
    ((half4*)out)[i] = h;
  }
}

// ------------- transpose+cast: in[K][N] fp32 -> out[N][K] fp16 -------------
__global__ void k_tcast(const float* __restrict__ in, f16* __restrict__ out, int K, int N) {
  __shared__ float tile[64][65];
  const int t = threadIdx.x;
  const int nb = blockIdx.x * 64, kb = blockIdx.y * 64;
  const int tr = t >> 4, tc4 = (t & 15) * 4;
  #pragma unroll
  for (int i = 0; i < 4; ++i) {
    int k = tr + i * 16;
    float4 v = *(const float4*)&in[(size_t)(kb + k) * N + nb + tc4];
    tile[k][tc4 + 0] = v.x; tile[k][tc4 + 1] = v.y;
    tile[k][tc4 + 2] = v.z; tile[k][tc4 + 3] = v.w;
  }
  __syncthreads();
  #pragma unroll
  for (int i = 0; i < 4; ++i) {
    int n = tr + i * 16;
    half4 h = { (f16)tile[tc4 + 0][n], (f16)tile[tc4 + 1][n],
                (f16)tile[tc4 + 2][n], (f16)tile[tc4 + 3][n] };
    *(half4*)&out[(size_t)(nb + n) * K + kb + tc4] = h;
  }
}

// ---------------- fp16 MFMA GEMM: C[M][N] = A[M][K] * Bt[N][K]^T ----------------
// m97 structure: 128x128 tile, BK=64, 4 waves (2x2 of 64x64),
// global_load_lds staging into LINEAR LDS, 2 barriers per K-step.
__global__ __launch_bounds__(256, 2) void k_gemm(
    const f16* __restrict__ A, const f16* __restrict__ Bt,
    f16* __restrict__ C16, float* __restrict__ C32,
    int M, int N, int K, int writeF32)
{
  __shared__ __attribute__((aligned(16))) f16 As[128 * 64];
  __shared__ __attribute__((aligned(16))) f16 Bs[128 * 64];
  const int t = threadIdx.x;
  const int lane = t & 63, wave = t >> 6;
  const int lr = lane & 15, hi4 = lane >> 4;
  const int wr = wave >> 1, wc = wave & 1;
  const int row0 = blockIdx.x * 128, col0 = blockIdx.y * 128;

  const int srow = lane >> 3, schunk = lane & 7;
  const f16* gA = &A[(size_t)(row0 + wave * 32 + srow) * K + schunk * 8];
  const f16* gB = &Bt[(size_t)(col0 + wave * 32 + srow) * K + schunk * 8];
  char* asb = (char*)As;
  char* bsb = (char*)Bs;

  f32x4 acc[4][4];
  #pragma unroll
  for (int m = 0; m < 4; ++m)
    #pragma unroll
    for (int n = 0; n < 4; ++n)
      acc[m][n] = (f32x4){0.f, 0.f, 0.f, 0.f};

  const int nk = K >> 6;
  for (int kt = 0; kt < nk; ++kt) {
    __syncthreads();
    #pragma unroll
    for (int i = 0; i < 4; ++i) {
      gload16(gA + (size_t)(i * 8) * K + kt * 64, asb + wave * 4096 + i * 1024);
      gload16(gB + (size_t)(i * 8) * K + kt * 64, bsb + wave * 4096 + i * 1024);
    }
    __syncthreads();
    #pragma unroll
    for (int ks = 0; ks < 2; ++ks) {
      half8 af[4], bf[4];
      #pragma unroll
      for (int m = 0; m < 4; ++m)
        af[m] = *(const half8*)(asb + (wr * 64 + m * 16 + lr) * 128 + ks * 64 + hi4 * 16);
      #pragma unroll
      for (int n = 0; n < 4; ++n)
        bf[n] = *(const half8*)(bsb + (wc * 64 + n * 16 + lr) * 128 + ks * 64 + hi4 * 16);
      #pragma unroll
      for (int m = 0; m < 4; ++m)
        #pragma unroll
        for (int n = 0; n < 4; ++n)
          acc[m][n] = __builtin_amdgcn_mfma_f32_16x16x32_f16(af[m], bf[n], acc[m][n], 0, 0, 0);
    }
  }
  #pragma unroll
  for (int m = 0; m < 4; ++m)
    #pragma unroll
    for (int n = 0; n < 4; ++n)
      #pragma unroll
      for (int j = 0; j < 4; ++j) {
        int row = row0 + wr * 64 + m * 16 + hi4 * 4 + j;
        int col = col0 + wc * 64 + n * 16 + lr;
        if (writeF32) C32[(size_t)row * N + col] = acc[m][n][j];
        else          C16[(size_t)row * N + col] = (f16)acc[m][n][j];
      }
  (void)M;
}

// ---------------- RoPE on q,k heads; writes Q (scaled) and K ----------------
__global__ void k_rope(const f16* __restrict__ qkv, const float* __restrict__ cosb,
                       const float* __restrict__ sinb, f16* __restrict__ Qf, f16* __restrict__ Kf)
{
  const int bx = blockIdx.x;              // B*S*16
  const int bs = bx >> 4;
  const int h = (bx & 15) * 2 + (threadIdx.x >> 7);   // 0..31 (q:0-15, k:16-31)
  const int d = threadIdx.x & 127;
  const int s = bs & (S_ - 1);
  const int b = bs >> 11;
  float x  = (float)qkv[(size_t)bs * EQ_ + h * HD_ + d];
  float xp = (float)qkv[(size_t)bs * EQ_ + h * HD_ + (d ^ 64)];
  float sgn = (d < 64) ? -1.0f : 1.0f;
  float v = x * cosb[s * HD_ + d] + sgn * xp * sinb[s * HD_ + d];
  if (h < H_) {
    v *= SCALE_Q;
    Qf[(((size_t)(b * H_ + h)) * S_ + s) * HD_ + d] = (f16)v;
  } else {
    Kf[(((size_t)(b * H_ + (h - H_))) * S_ + s) * HD_ + d] = (f16)v;
  }
}

// ---------------- V transpose: qkv v-heads -> VT[B][H][D][S] fp16 ----------------
__global__ void k_vtrans(const f16* __restrict__ qkv, f16* __restrict__ VT)
{
  __shared__ __attribute__((aligned(16))) f16 tile[128][136];
  const int bx = blockIdx.x;              // B*H*(S/128) = 512
  const int st = bx & 15, h = (bx >> 4) & 15, b = bx >> 8;
  const int t = threadIdx.x;
  const int sl = t >> 1, dc = (t & 1) * 64;
  const int bs = b * S_ + st * 128 + sl;
  #pragma unroll
  for (int i = 0; i < 8; ++i) {
    half8 v = *(const half8*)&qkv[(size_t)bs * EQ_ + (32 + h) * HD_ + dc + i * 8];
    *(half8*)&tile[sl][dc + i * 8] = v;
  }
  __syncthreads();
  const int dr = t >> 1, scc = (t & 1) * 64;
  #pragma unroll
  for (int i = 0; i < 8; ++i) {
    half8 v;
    #pragma unroll
    for (int j = 0; j < 8; ++j) v[j] = tile[scc + i * 8 + j][dr];
    *(half8*)&VT[(((size_t)(b * H_ + h)) * HD_ + dr) * S_ + st * 128 + scc + i * 8] = v;
  }
}

// ---------------- flash attention: 4 waves x 32 q-rows, KT=64 ----------------
// 32KB LDS (P reuses Ks region after QK), gload_lds staging with pre-swizzled
// global source (rule #21), DPP reductions, defer-max (T13).
// launch_bounds (256,2): (256,4) capped unified VGPR+AGPR at 128/wave and the
// 64-reg accumulator forced catastrophic scratch spill (R4: 10x HBM traffic).
__global__ __launch_bounds__(256, 2) void k_attn(
    const f16* __restrict__ Qf, const f16* __restrict__ Kf, const f16* __restrict__ VT,
    f16* __restrict__ Oout)
{
  __shared__ __attribute__((aligned(16))) char lds[32768];
  char* Ks = lds;                        // [64 tok][128 d], 256B rows, chunk^(row&7)
  char* Vs = lds + 16384;                // [128 d][64 tok], 128B rows, chunk^(row&7)
  const int bx = blockIdx.x;             // B*H*(S/128) = 512
  const int qt = bx & 15, h = (bx >> 4) & 15, b = bx >> 8;
  const int t = threadIdx.x, lane = t & 63, wave = t >> 6;
  const int lr = lane & 15, hi4 = lane >> 4;
  char* Ps = Ks + wave * 4096;           // after QK: per-wave [32 q][64 tok] swizzled
  const size_t bh = (size_t)(b * H_ + h);
  const int q0 = qt * 128 + wave * 32;

  half8 qf[2][4];
  #pragma unroll
  for (int m = 0; m < 2; ++m)
    #pragma unroll
    for (int ds = 0; ds < 4; ++ds)
      qf[m][ds] = *(const half8*)&Qf[(bh * S_ + q0 + m * 16 + lr) * HD_ + ds * 32 + hi4 * 8];

  f32x4 o[2][8];
  #pragma unroll
  for (int m = 0; m < 2; ++m)
    #pragma unroll
    for (int dc = 0; dc < 8; ++dc) o[m][dc] = (f32x4){0.f, 0.f, 0.f, 0.f};
  float mstate[2][4], lstate[2][4];
  #pragma unroll
  for (int m = 0; m < 2; ++m)
    #pragma unroll
    for (int j = 0; j < 4; ++j) { mstate[m][j] = -1e30f; lstate[m][j] = 0.f; }

  const f16* Kg = &Kf[bh * S_ * HD_];
  const f16* Vg = &VT[bh * HD_ * S_];

  for (int kt = 0; kt < S_ / 64; ++kt) {
    __syncthreads();
    // K stage: wave w covers rows w*16..w*16+15; LDS linear = base + lane*16;
    // global chunk pre-swizzled so LDS[row][c] = K[row][c ^ (row&7)]
    #pragma unroll
    for (int i = 0; i < 4; ++i) {
      int row = wave * 16 + i * 4 + (lane >> 4);
      int ch  = (lane & 15) ^ (row & 7);
      gload16(Kg + (size_t)(kt * 64 + row) * HD_ + ch * 8, Ks + wave * 4096 + i * 1024);
    }
    // V stage: wave w covers d-rows w*32..w*32+31
    #pragma unroll
    for (int i = 0; i < 4; ++i) {
      int d  = wave * 32 + i * 8 + (lane >> 3);
      int ch = (lane & 7) ^ (d & 7);
      gload16(Vg + (size_t)d * S_ + kt * 64 + ch * 8, Vs + wave * 4096 + i * 1024);
    }
    __syncthreads();   // drains vmcnt; staged K/V visible

    f32x4 sc[2][4];
    #pragma unroll
    for (int m = 0; m < 2; ++m)
      #pragma unroll
      for (int n = 0; n < 4; ++n) sc[m][n] = (f32x4){0.f, 0.f, 0.f, 0.f};
    #pragma unroll
    for (int ds = 0; ds < 4; ++ds) {
      half8 kf[4];
      #pragma unroll
      for (int n = 0; n < 4; ++n) {
        int ar = n * 16 + lr;
        kf[n] = *(const half8*)(Ks + ar * 256 + ((((ds * 4 + hi4) ^ (ar & 7))) << 4));
      }
      #pragma unroll
      for (int m = 0; m < 2; ++m)
        #pragma unroll
        for (int n = 0; n < 4; ++n)
          sc[m][n] = __builtin_amdgcn_mfma_f32_16x16x32_f16(qf[m][ds], kf[n], sc[m][n], 0, 0, 0);
    }
    __syncthreads();   // all Ks reads complete; Ks region now reusable for P

    // ---- online softmax (natural log, __expf fast path, DPP reductions) ----
    float mx[2][4];
    #pragma unroll
    for (int m = 0; m < 2; ++m)
      #pragma unroll
      for (int j = 0; j < 4; ++j) {
        mx[m][j] = fmaxf(fmaxf(sc[m][0][j], sc[m][1][j]), fmaxf(sc[m][2][j], sc[m][3][j]));
        mx[m][j] = red16_max(mx[m][j]);
      }
    // defer-max: skip rescale unless some row's max grew by > THR
    float dmax = -1e30f;
    #pragma unroll
    for (int m = 0; m < 2; ++m)
      #pragma unroll
      for (int j = 0; j < 4; ++j)
        dmax = fmaxf(dmax, mx[m][j] - mstate[m][j]);
    if (__any(dmax > DEFER_THR)) {
      #pragma unroll
      for (int m = 0; m < 2; ++m)
        #pragma unroll
        for (int j = 0; j < 4; ++j) {
          float nm = fmaxf(mstate[m][j], mx[m][j]);
          float corr = __expf(mstate[m][j] - nm);
          mstate[m][j] = nm;
          lstate[m][j] *= corr;
          #pragma unroll
          for (int dc = 0; dc < 8; ++dc) o[m][dc][j] *= corr;
        }
    }
    float rs[2][4];
    #pragma unroll
    for (int m = 0; m < 2; ++m)
      #pragma unroll
      for (int j = 0; j < 4; ++j) rs[m][j] = 0.f;
    #pragma unroll
    for (int m = 0; m < 2; ++m)
      #pragma unroll
      for (int n = 0; n < 4; ++n)
        #pragma unroll
        for (int j = 0; j < 4; ++j) {
          float p = __expf(sc[m][n][j] - mstate[m][j]);
          sc[m][n][j] = p;
          rs[m][j] += p;
        }
    #pragma unroll
    for (int m = 0; m < 2; ++m)
      #pragma unroll
      for (int j = 0; j < 4; ++j)
        lstate[m][j] += red16_sum(rs[m][j]);

    // ---- P -> per-wave LDS (fp16, swizzled, in Ks region) ----
    #pragma unroll
    for (int m = 0; m < 2; ++m)
      #pragma unroll
      for (int n = 0; n < 4; ++n)
        #pragma unroll
        for (int j = 0; j < 4; ++j) {
          int prow = m * 16 + hi4 * 4 + j;
          *(f16*)(Ps + prow * 128 + ((n * 32 + lr * 2) ^ ((prow & 7) << 4))) = (f16)sc[m][n][j];
        }
    asm volatile("" ::: "memory");  // per-wave LDS ordering: DS ops in-order per wave

    #pragma unroll
    for (int ks = 0; ks < 2; ++ks) {
      half8 pa[2];
      #pragma unroll
      for (int m = 0; m < 2; ++m) {
        int pr = m * 16 + lr;
        pa[m] = *(const half8*)(Ps + pr * 128 + ((((ks * 4 + hi4) ^ (pr & 7))) << 4));
      }
      #pragma unroll
      for (int dc = 0; dc < 8; ++dc) {
        int rv = dc * 16 + lr;
        half8 vb = *(const half8*)(Vs + rv * 128 + ((((ks * 4 + hi4) ^ (rv & 7))) << 4));
        #pragma unroll
        for (int m = 0; m < 2; ++m)
          o[m][dc] = __builtin_amdgcn_mfma_f32_16x16x32_f16(pa[m], vb, o[m][dc], 0, 0, 0);
      }
    }
  }

  float inv[2][4];
  #pragma unroll
  for (int m = 0; m < 2; ++m)
    #pragma unroll
    for (int j = 0; j < 4; ++j) inv[m][j] = 1.0f / lstate[m][j];
  #pragma unroll
  for (int m = 0; m < 2; ++m)
    #pragma unroll
    for (int dc = 0; dc < 8; ++dc)
      #pragma unroll
      for (int j = 0; j < 4; ++j) {
        int row = b * S_ + qt * 128 + wave * 32 + m * 16 + hi4 * 4 + j;
        int col = h * 128 + dc * 16 + lr;
        Oout[(size_t)row * DM_ + col] = (f16)(o[m][dc][j] * inv[m][j]);
      }
}

extern "C" void kernel_launch(void* const* d_in, const int* in_sizes, int n_in,
                              void* d_out, int out_size, void* d_ws, size_t ws_size,
                              hipStream_t stream) {
  (void)in_sizes; (void)n_in; (void)out_size; (void)ws_size;
  const float* hidden = (const float*)d_in[0];
  const float* cosb   = (const float*)d_in[1];
  const float* sinb   = (const float*)d_in[2];
  const float* W_qkv  = (const float*)d_in[3];
  const float* W_o    = (const float*)d_in[4];
  float* out = (float*)d_out;

  f16* Ah    = (f16*)d_ws;                 // [4096][2048]
  f16* Wqt   = Ah    + (size_t)8388608;    // [6144][2048]
  f16* Wot   = Wqt   + (size_t)12582912;   // [2048][2048]
  f16* qkv16 = Wot   + (size_t)4194304;    // [4096][6144]
  f16* Qf    = qkv16 + (size_t)25165824;   // [2][16][2048][128]
  f16* Kf    = Qf    + (size_t)8388608;
  f16* VT    = Kf    + (size_t)8388608;    // [2][16][128][2048]
  f16* AO    = VT    + (size_t)8388608;    // [4096][2048]

  k_cast<<<2048, 256, 0, stream>>>(hidden, Ah, 2097152);
  k_tcast<<<dim3(EQ_ / 64, 2048 / 64), 256, 0, stream>>>(W_qkv, Wqt, 2048, EQ_);
  k_tcast<<<dim3(2048 / 64, 2048 / 64), 256, 0, stream>>>(W_o, Wot, 2048, 2048);
  k_gemm<<<dim3(32, EQ_ / 128), 256, 0, stream>>>(Ah, Wqt, qkv16, nullptr, 4096, EQ_, 2048, 0);
  k_rope<<<B_ * S_ * 16, 256, 0, stream>>>(qkv16, cosb, sinb, Qf, Kf);
  k_vtrans<<<512, 256, 0, stream>>>(qkv16, VT);
  k_attn<<<512, 256, 0, stream>>>(Qf, Kf, VT, AO);
  k_gemm<<<dim3(32, 16), 256, 0, stream>>>(AO, Wot, nullptr, out, 4096, 2048, 2048, 1);
}

// Round 6
// 433.924 us; speedup vs baseline: 1.9716x; 1.0593x over previous
//
#include <hip/hip_runtime.h>

typedef _Float16 f16;
typedef _Float16 half8 __attribute__((ext_vector_type(8)));
typedef _Float16 half4 __attribute__((ext_vector_type(4)));
typedef float f32x4 __attribute__((ext_vector_type(4)));

#define B_ 2
#define S_ 2048
#define DM_ 2048
#define H_ 16
#define HD_ 128
#define EQ_ 6144              // (H + 2*HKV) * HD = 48*128
#define SCALE_Q 0.08838834764831845f   // 1/sqrt(128); natural-log softmax, __expf is fast
#define DEFER_THR 8.0f

// async global->LDS, 16B per lane; LDS dest is wave-uniform base + lane*16
__device__ __forceinline__ void gload16(const void* g, void* l) {
  __builtin_amdgcn_global_load_lds(
      (const __attribute__((address_space(1))) unsigned int*)g,
      (__attribute__((address_space(3))) unsigned int*)l, 16, 0, 0);
}

// 16-lane reductions via DPP (VALU-speed, no DS pipe)
__device__ __forceinline__ float red16_max(float x) {
  float t;
  t = __builtin_bit_cast(float, __builtin_amdgcn_mov_dpp(__builtin_bit_cast(int, x), 0xB1, 0xF, 0xF, true));
  x = fmaxf(x, t);
  t = __builtin_bit_cast(float, __builtin_amdgcn_mov_dpp(__builtin_bit_cast(int, x), 0x4E, 0xF, 0xF, true));
  x = fmaxf(x, t);
  t = __builtin_bit_cast(float, __builtin_amdgcn_mov_dpp(__builtin_bit_cast(int, x), 0x141, 0xF, 0xF, true));
  x = fmaxf(x, t);
  t = __builtin_bit_cast(float, __builtin_amdgcn_mov_dpp(__builtin_bit_cast(int, x), 0x140, 0xF, 0xF, true));
  x = fmaxf(x, t);
  return x;
}
__device__ __forceinline__ float red16_sum(float x) {
  float t;
  t = __builtin_bit_cast(float, __builtin_amdgcn_mov_dpp(__builtin_bit_cast(int, x), 0xB1, 0xF, 0xF, true));
  x += t;
  t = __builtin_bit_cast(float, __builtin_amdgcn_mov_dpp(__builtin_bit_cast(int, x), 0x4E, 0xF, 0xF, true));
  x += t;
  t = __builtin_bit_cast(float, __builtin_amdgcn_mov_dpp(__builtin_bit_cast(int, x), 0x141, 0xF, 0xF, true));
  x += t;
  t = __builtin_bit_cast(float, __builtin_amdgcn_mov_dpp(__builtin_bit_cast(int, x), 0x140, 0xF, 0xF, true));
  x += t;
  return x;
}

// ---------------- cast fp32 -> fp16 (same layout) ----------------
__global__ void k_cast(const float* __restrict__ in, f16* __restrict__ out, int n4) {
  int i = blockIdx.x * blockDim.x + threadIdx.x;
  int stride = gridDim.x * blockDim.x;
  for (; i < n4; i += stride) {
    float4 v = ((const float4*)in)[i];
    half4 h = { (f16)v.x, (f16)v.y, (f16)v.z, (f16)v.w };
    ((half4*)out)[i] = h;
  }
}

// ------------- transpose+cast: in[K][N] fp32 -> out[N][K] fp16 -------------
__global__ void k_tcast(const float* __restrict__ in, f16* __restrict__ out, int K, int N) {
  __shared__ float tile[64][65];
  const int t = threadIdx.x;
  const int nb = blockIdx.x * 64, kb = blockIdx.y * 64;
  const int tr = t >> 4, tc4 = (t & 15) * 4;
  #pragma unroll
  for (int i = 0; i < 4; ++i) {
    int k = tr + i * 16;
    float4 v = *(const float4*)&in[(size_t)(kb + k) * N + nb + tc4];
    tile[k][tc4 + 0] = v.x; tile[k][tc4 + 1] = v.y;
    tile[k][tc4 + 2] = v.z; tile[k][tc4 + 3] = v.w;
  }
  __syncthreads();
  #pragma unroll
  for (int i = 0; i < 4; ++i) {
    int n = tr + i * 16;
    half4 h = { (f16)tile[tc4 + 0][n], (f16)tile[tc4 + 1][n],
                (f16)tile[tc4 + 2][n], (f16)tile[tc4 + 3][n] };
    *(half4*)&out[(size_t)(nb + n) * K + kb + tc4] = h;
  }
}

// ---------------- fp16 MFMA GEMM: C[M][N] = A[M][K] * Bt[N][K]^T ----------------
// 128x128 tile, BK=64, 4 waves (2x2 of 64x64). Double-buffered LDS with
// global_load_lds prefetch (T3-min: stage t+1 before compute t, one barrier/tile)
// and T2 XOR swizzle via pre-swizzled GLOBAL source + swizzled LDS reads.
__global__ __launch_bounds__(256, 2) void k_gemm(
    const f16* __restrict__ A, const f16* __restrict__ Bt,
    f16* __restrict__ C16, float* __restrict__ C32,
    int M, int N, int K, int writeF32)
{
  __shared__ __attribute__((aligned(16))) f16 As[2 * 128 * 64];  // 2 x 16KB
  __shared__ __attribute__((aligned(16))) f16 Bs[2 * 128 * 64];
  const int t = threadIdx.x;
  const int lane = t & 63, wave = t >> 6;
  const int lr = lane & 15, hi4 = lane >> 4;
  const int wr = wave >> 1, wc = wave & 1;
  const int row0 = blockIdx.x * 128, col0 = blockIdx.y * 128;

  // staging: wave w instr i covers rows w*32+i*8 .. +8; lane l -> row +(l>>3),
  // 16B chunk (l&7). Source chunk pre-swizzled: LDS[row][c] = G[row][c^(row&7)]
  const int srow = lane >> 3, schunk = lane & 7;
  const f16* gA = &A[(size_t)(row0 + wave * 32 + srow) * K + ((schunk ^ srow) * 8)];
  const f16* gB = &Bt[(size_t)(col0 + wave * 32 + srow) * K + ((schunk ^ srow) * 8)];
  char* asb = (char*)As;
  char* bsb = (char*)Bs;

  f32x4 acc[4][4];
  #pragma unroll
  for (int m = 0; m < 4; ++m)
    #pragma unroll
    for (int n = 0; n < 4; ++n)
      acc[m][n] = (f32x4){0.f, 0.f, 0.f, 0.f};

  const int nk = K >> 6;
  // prologue: stage tile 0 into buf 0
  #pragma unroll
  for (int i = 0; i < 4; ++i) {
    gload16(gA + (size_t)(i * 8) * K, asb + wave * 4096 + i * 1024);
    gload16(gB + (size_t)(i * 8) * K, bsb + wave * 4096 + i * 1024);
  }
  __syncthreads();

  int cur = 0;
  for (int kt = 0; kt < nk; ++kt) {
    // prefetch next tile into the other buffer (overlaps with MFMA below)
    if (kt + 1 < nk) {
      int nb = cur ^ 1;
      #pragma unroll
      for (int i = 0; i < 4; ++i) {
        gload16(gA + (size_t)(i * 8) * K + (kt + 1) * 64, asb + nb * 16384 + wave * 4096 + i * 1024);
        gload16(gB + (size_t)(i * 8) * K + (kt + 1) * 64, bsb + nb * 16384 + wave * 4096 + i * 1024);
      }
    }
    const char* ab = asb + cur * 16384;
    const char* bb = bsb + cur * 16384;
    #pragma unroll
    for (int ks = 0; ks < 2; ++ks) {
      half8 af[4], bf[4];
      #pragma unroll
      for (int m = 0; m < 4; ++m) {
        int ar = wr * 64 + m * 16 + lr;
        af[m] = *(const half8*)(ab + ar * 128 + (((ks * 4 + hi4) ^ (ar & 7)) << 4));
      }
      #pragma unroll
      for (int n = 0; n < 4; ++n) {
        int br = wc * 64 + n * 16 + lr;
        bf[n] = *(const half8*)(bb + br * 128 + (((ks * 4 + hi4) ^ (br & 7)) << 4));
      }
      #pragma unroll
      for (int m = 0; m < 4; ++m)
        #pragma unroll
        for (int n = 0; n < 4; ++n)
          acc[m][n] = __builtin_amdgcn_mfma_f32_16x16x32_f16(af[m], bf[n], acc[m][n], 0, 0, 0);
    }
    __syncthreads();   // drains vmcnt(0): prefetch landed; all reads of cur done
    cur ^= 1;
  }
  #pragma unroll
  for (int m = 0; m < 4; ++m)
    #pragma unroll
    for (int n = 0; n < 4; ++n)
      #pragma unroll
      for (int j = 0; j < 4; ++j) {
        int row = row0 + wr * 64 + m * 16 + hi4 * 4 + j;
        int col = col0 + wc * 64 + n * 16 + lr;
        if (writeF32) C32[(size_t)row * N + col] = acc[m][n][j];
        else          C16[(size_t)row * N + col] = (f16)acc[m][n][j];
      }
  (void)M;
}

// ---------------- RoPE on q,k heads; writes Q (scaled) and K ----------------
__global__ void k_rope(const f16* __restrict__ qkv, const float* __restrict__ cosb,
                       const float* __restrict__ sinb, f16* __restrict__ Qf, f16* __restrict__ Kf)
{
  const int bx = blockIdx.x;              // B*S*16
  const int bs = bx >> 4;
  const int h = (bx & 15) * 2 + (threadIdx.x >> 7);   // 0..31 (q:0-15, k:16-31)
  const int d = threadIdx.x & 127;
  const int s = bs & (S_ - 1);
  const int b = bs >> 11;
  float x  = (float)qkv[(size_t)bs * EQ_ + h * HD_ + d];
  float xp = (float)qkv[(size_t)bs * EQ_ + h * HD_ + (d ^ 64)];
  float sgn = (d < 64) ? -1.0f : 1.0f;
  float v = x * cosb[s * HD_ + d] + sgn * xp * sinb[s * HD_ + d];
  if (h < H_) {
    v *= SCALE_Q;
    Qf[(((size_t)(b * H_ + h)) * S_ + s) * HD_ + d] = (f16)v;
  } else {
    Kf[(((size_t)(b * H_ + (h - H_))) * S_ + s) * HD_ + d] = (f16)v;
  }
}

// ---------------- V transpose: qkv v-heads -> VT[B][H][D][S] fp16 ----------------
__global__ void k_vtrans(const f16* __restrict__ qkv, f16* __restrict__ VT)
{
  __shared__ __attribute__((aligned(16))) f16 tile[128][136];
  const int bx = blockIdx.x;              // B*H*(S/128) = 512
  const int st = bx & 15, h = (bx >> 4) & 15, b = bx >> 8;
  const int t = threadIdx.x;
  const int sl = t >> 1, dc = (t & 1) * 64;
  const int bs = b * S_ + st * 128 + sl;
  #pragma unroll
  for (int i = 0; i < 8; ++i) {
    half8 v = *(const half8*)&qkv[(size_t)bs * EQ_ + (32 + h) * HD_ + dc + i * 8];
    *(half8*)&tile[sl][dc + i * 8] = v;
  }
  __syncthreads();
  const int dr = t >> 1, scc = (t & 1) * 64;
  #pragma unroll
  for (int i = 0; i < 8; ++i) {
    half8 v;
    #pragma unroll
    for (int j = 0; j < 8; ++j) v[j] = tile[scc + i * 8 + j][dr];
    *(half8*)&VT[(((size_t)(b * H_ + h)) * HD_ + dr) * S_ + st * 128 + scc + i * 8] = v;
  }
}

// ---------------- flash attention: 4 waves x 32 q-rows, KT=64 ----------------
// Block remap: bx%32 = head-global -> all 16 q-tiles of a head share an XCD
// (bx%8 == head%8) so K/V staging hits that XCD's L2 instead of HBM.
// Counted vmcnt: wait only the 4 K-loads before QK; V-loads fly under QK.
__global__ __launch_bounds__(256, 2) void k_attn(
    const f16* __restrict__ Qf, const f16* __restrict__ Kf, const f16* __restrict__ VT,
    f16* __restrict__ Oout)
{
  __shared__ __attribute__((aligned(16))) char lds[32768];
  char* Ks = lds;                        // [64 tok][128 d], 256B rows, chunk^(row&7)
  char* Vs = lds + 16384;                // [128 d][64 tok], 128B rows, chunk^(row&7)
  const int bx = blockIdx.x;             // B*H*(S/128) = 512
  const int hg = bx & 31, qt = bx >> 5;  // head-major: same head => same XCD residue
  const int h = hg & 15, b = hg >> 4;
  const int t = threadIdx.x, lane = t & 63, wave = t >> 6;
  const int lr = lane & 15, hi4 = lane >> 4;
  char* Ps = Ks + wave * 4096;           // after QK: per-wave [32 q][64 tok] swizzled
  const size_t bh = (size_t)(b * H_ + h);
  const int q0 = qt * 128 + wave * 32;

  half8 qf[2][4];
  #pragma unroll
  for (int m = 0; m < 2; ++m)
    #pragma unroll
    for (int ds = 0; ds < 4; ++ds)
      qf[m][ds] = *(const half8*)&Qf[(bh * S_ + q0 + m * 16 + lr) * HD_ + ds * 32 + hi4 * 8];

  f32x4 o[2][8];
  #pragma unroll
  for (int m = 0; m < 2; ++m)
    #pragma unroll
    for (int dc = 0; dc < 8; ++dc) o[m][dc] = (f32x4){0.f, 0.f, 0.f, 0.f};
  float mstate[2][4], lstate[2][4];
  #pragma unroll
  for (int m = 0; m < 2; ++m)
    #pragma unroll
    for (int j = 0; j < 4; ++j) { mstate[m][j] = -1e30f; lstate[m][j] = 0.f; }

  const f16* Kg = &Kf[bh * S_ * HD_];
  const f16* Vg = &VT[bh * HD_ * S_];

  for (int kt = 0; kt < S_ / 64; ++kt) {
    __syncthreads();   // prior PV reads done before staging overwrites K/V
    // K stage first (QK needs it), V stage second (overlaps QK)
    #pragma unroll
    for (int i = 0; i < 4; ++i) {
      int row = wave * 16 + i * 4 + (lane >> 4);
      int ch  = (lane & 15) ^ (row & 7);
      gload16(Kg + (size_t)(kt * 64 + row) * HD_ + ch * 8, Ks + wave * 4096 + i * 1024);
    }
    #pragma unroll
    for (int i = 0; i < 4; ++i) {
      int d  = wave * 32 + i * 8 + (lane >> 3);
      int ch = (lane & 7) ^ (d & 7);
      gload16(Vg + (size_t)d * S_ + kt * 64 + ch * 8, Vs + wave * 4096 + i * 1024);
    }
    // wait only the 4 K-loads (last 4 outstanding are V); barrier all waves
    asm volatile("s_waitcnt vmcnt(4)" ::: "memory");
    __builtin_amdgcn_s_barrier();
    __builtin_amdgcn_sched_barrier(0);   // rule #18: keep ds_reads below

    f32x4 sc[2][4];
    #pragma unroll
    for (int m = 0; m < 2; ++m)
      #pragma unroll
      for (int n = 0; n < 4; ++n) sc[m][n] = (f32x4){0.f, 0.f, 0.f, 0.f};
    #pragma unroll
    for (int ds = 0; ds < 4; ++ds) {
      half8 kf[4];
      #pragma unroll
      for (int n = 0; n < 4; ++n) {
        int ar = n * 16 + lr;
        kf[n] = *(const half8*)(Ks + ar * 256 + ((((ds * 4 + hi4) ^ (ar & 7))) << 4));
      }
      #pragma unroll
      for (int m = 0; m < 2; ++m)
        #pragma unroll
        for (int n = 0; n < 4; ++n)
          sc[m][n] = __builtin_amdgcn_mfma_f32_16x16x32_f16(qf[m][ds], kf[n], sc[m][n], 0, 0, 0);
    }
    __syncthreads();   // drains vmcnt(0): V visible; Ks reads done -> reusable as Ps

    // ---- online softmax (natural log, __expf fast path, DPP reductions) ----
    float mx[2][4];
    #pragma unroll
    for (int m = 0; m < 2; ++m)
      #pragma unroll
      for (int j = 0; j < 4; ++j) {
        mx[m][j] = fmaxf(fmaxf(sc[m][0][j], sc[m][1][j]), fmaxf(sc[m][2][j], sc[m][3][j]));
        mx[m][j] = red16_max(mx[m][j]);
      }
    // defer-max: skip rescale unless some row's max grew by > THR
    float dmax = -1e30f;
    #pragma unroll
    for (int m = 0; m < 2; ++m)
      #pragma unroll
      for (int j = 0; j < 4; ++j)
        dmax = fmaxf(dmax, mx[m][j] - mstate[m][j]);
    if (__any(dmax > DEFER_THR)) {
      #pragma unroll
      for (int m = 0; m < 2; ++m)
        #pragma unroll
        for (int j = 0; j < 4; ++j) {
          float nm = fmaxf(mstate[m][j], mx[m][j]);
          float corr = __expf(mstate[m][j] - nm);
          mstate[m][j] = nm;
          lstate[m][j] *= corr;
          #pragma unroll
          for (int dc = 0; dc < 8; ++dc) o[m][dc][j] *= corr;
        }
    }
    float rs[2][4];
    #pragma unroll
    for (int m = 0; m < 2; ++m)
      #pragma unroll
      for (int j = 0; j < 4; ++j) rs[m][j] = 0.f;
    #pragma unroll
    for (int m = 0; m < 2; ++m)
      #pragma unroll
      for (int n = 0; n < 4; ++n)
        #pragma unroll
        for (int j = 0; j < 4; ++j) {
          float p = __expf(sc[m][n][j] - mstate[m][j]);
          sc[m][n][j] = p;
          rs[m][j] += p;
        }
    #pragma unroll
    for (int m = 0; m < 2; ++m)
      #pragma unroll
      for (int j = 0; j < 4; ++j)
        lstate[m][j] += red16_sum(rs[m][j]);

    // ---- P -> per-wave LDS (fp16, swizzled, in Ks region) ----
    #pragma unroll
    for (int m = 0; m < 2; ++m)
      #pragma unroll
      for (int n = 0; n < 4; ++n)
        #pragma unroll
        for (int j = 0; j < 4; ++j) {
          int prow = m * 16 + hi4 * 4 + j;
          *(f16*)(Ps + prow * 128 + ((n * 32 + lr * 2) ^ ((prow & 7) << 4))) = (f16)sc[m][n][j];
        }
    asm volatile("" ::: "memory");  // per-wave LDS ordering: DS ops in-order per wave

    #pragma unroll
    for (int ks = 0; ks < 2; ++ks) {
      half8 pa[2];
      #pragma unroll
      for (int m = 0; m < 2; ++m) {
        int pr = m * 16 + lr;
        pa[m] = *(const half8*)(Ps + pr * 128 + ((((ks * 4 + hi4) ^ (pr & 7))) << 4));
      }
      #pragma unroll
      for (int dc = 0; dc < 8; ++dc) {
        int rv = dc * 16 + lr;
        half8 vb = *(const half8*)(Vs + rv * 128 + ((((ks * 4 + hi4) ^ (rv & 7))) << 4));
        #pragma unroll
        for (int m = 0; m < 2; ++m)
          o[m][dc] = __builtin_amdgcn_mfma_f32_16x16x32_f16(pa[m], vb, o[m][dc], 0, 0, 0);
      }
    }
  }

  float inv[2][4];
  #pragma unroll
  for (int m = 0; m < 2; ++m)
    #pragma unroll
    for (int j = 0; j < 4; ++j) inv[m][j] = 1.0f / lstate[m][j];
  #pragma unroll
  for (int m = 0; m < 2; ++m)
    #pragma unroll
    for (int dc = 0; dc < 8; ++dc)
      #pragma unroll
      for (int j = 0; j < 4; ++j) {
        int row = b * S_ + qt * 128 + wave * 32 + m * 16 + hi4 * 4 + j;
        int col = h * 128 + dc * 16 + lr;
        Oout[(size_t)row * DM_ + col] = (f16)(o[m][dc][j] * inv[m][j]);
      }
}

extern "C" void kernel_launch(void* const* d_in, const int* in_sizes, int n_in,
                              void* d_out, int out_size, void* d_ws, size_t ws_size,
                              hipStream_t stream) {
  (void)in_sizes; (void)n_in; (void)out_size; (void)ws_size;
  const float* hidden = (const float*)d_in[0];
  const float* cosb   = (const float*)d_in[1];
  const float* sinb   = (const float*)d_in[2];
  const float* W_qkv  = (const float*)d_in[3];
  const float* W_o    = (const float*)d_in[4];
  float* out = (float*)d_out;

  f16* Ah    = (f16*)d_ws;                 // [4096][2048]
  f16* Wqt   = Ah    + (size_t)8388608;    // [6144][2048]
  f16* Wot   = Wqt   + (size_t)12582912;   // [2048][2048]
  f16* qkv16 = Wot   + (size_t)4194304;    // [4096][6144]
  f16* Qf    = qkv16 + (size_t)25165824;   // [2][16][2048][128]
  f16* Kf    = Qf    + (size_t)8388608;
  f16* VT    = Kf    + (size_t)8388608;    // [2][16][128][2048]
  f16* AO    = VT    + (size_t)8388608;    // [4096][2048]

  k_cast<<<2048, 256, 0, stream>>>(hidden, Ah, 2097152);
  k_tcast<<<dim3(EQ_ / 64, 2048 / 64), 256, 0, stream>>>(W_qkv, Wqt, 2048, EQ_);
  k_tcast<<<dim3(2048 / 64, 2048 / 64), 256, 0, stream>>>(W_o, Wot, 2048, 2048);
  k_gemm<<<dim3(32, EQ_ / 128), 256, 0, stream>>>(Ah, Wqt, qkv16, nullptr, 4096, EQ_, 2048, 0);
  k_rope<<<B_ * S_ * 16, 256, 0, stream>>>(qkv16, cosb, sinb, Qf, Kf);
  k_vtrans<<<512, 256, 0, stream>>>(qkv16, VT);
  k_attn<<<512, 256, 0, stream>>>(Qf, Kf, VT, AO);
  k_gemm<<<dim3(32, 16), 256, 0, stream>>>(AO, Wot, nullptr, out, 4096, 2048, 2048, 1);
}